// Round 3
// baseline (87.314 us; speedup 1.0000x reference)
//
#include <hip/hip_runtime.h>
#include <math.h>

typedef _Float16 f16x8 __attribute__((ext_vector_type(8)));
typedef _Float16 f16x2 __attribute__((ext_vector_type(2)));
typedef float    f32x4 __attribute__((ext_vector_type(4)));

union F16x8u { f16x8 v; f16x2 h[4]; };

// v_sin_f32 / v_cos_f32 take REVOLUTIONS: sin(2*pi*x) = v_sin(x).
__device__ __forceinline__ float cos1_hw(float x) { return __builtin_amdgcn_cosf(x); }
__device__ __forceinline__ float sin1_hw(float x) { return __builtin_amdgcn_sinf(x); }

// v_cvt_pkrtz_f16_f32 returns a __fp16 vector; bit-cast to our _Float16 pair.
__device__ __forceinline__ f16x2 pkrtz(float a, float b)
{
    return __builtin_bit_cast(f16x2, __builtin_amdgcn_cvt_pkrtz(a, b));
}

// ---------------------------------------------------------------------------
// Complex NUFFT via MFMA (round 9):
//   ynew = (1/4096) Re sum_{k,m} F[k,m] e^{2pi i x1 f(k)} e^{2pi i x2 f(m)}
// Round-8 lesson: cot-form (rcp-heavy) and complex-form (rotation-only) both
// land at ~40 us -> NOT pipe-throughput-bound; latency/occupancy-bound.
// Round-9 changes, all aimed at wave overlap / chain depth:
//   * launch_bounds(256,4): grid is exactly 4 blocks/CU; (256,3) left a
//     256-block tail running at 1/3 occupancy.
//   * two-seed rotation (step rot^2) halves the B-fragment dep chain 7->3.
//   * stage-B nt bases by rotation from one seed: 6 trans/mt instead of 10,
//     setup chain ~8cy instead of ~30cy.
// ---------------------------------------------------------------------------

// Pass 1: T[b][n2][k] = sum_n1 y[b,n1,n2] e^{-2pi i k n1/64}   (half2 r,i)
__global__ __launch_bounds__(256)
void dft_pass1(const float* __restrict__ y, f16x2* __restrict__ T)
{
    __shared__ float  YL[4096];
    __shared__ float2 tw[64];
    const int tid = threadIdx.x;
    const int b = blockIdx.x >> 3;
    const int g = blockIdx.x & 7;

    const float4* src = (const float4*)(y + (b << 12));
    float4* dst = (float4*)YL;
#pragma unroll
    for (int i = 0; i < 4; ++i) dst[tid + (i << 8)] = src[tid + (i << 8)];
    if (tid < 64) {
        const float a = (float)tid * (1.0f / 64.0f);
        tw[tid] = make_float2(cos1_hw(a), sin1_hw(a));
    }
    __syncthreads();

    const int k   = tid & 63;          // lane = k  (coalesced output)
    const int wv  = tid >> 6;
    const int n2a = (g << 3) + wv;
    const int n2b = n2a + 4;

    float Tr0 = 0.f, Ti0 = 0.f, Tr1 = 0.f, Ti1 = 0.f;
#pragma unroll 4
    for (int n1 = 0; n1 < 64; ++n1) {
        const float ya = YL[(n1 << 6) + n2a];   // wave-uniform -> broadcast
        const float yb = YL[(n1 << 6) + n2b];
        const float2 w = tw[(k * n1) & 63];     // e^{-i t}: (c, -s)
        Tr0 = fmaf(ya,  w.x, Tr0);
        Ti0 = fmaf(ya, -w.y, Ti0);
        Tr1 = fmaf(yb,  w.x, Tr1);
        Ti1 = fmaf(yb, -w.y, Ti1);
    }
    T[(b << 12) + (n2a << 6) + k] = pkrtz(Tr0, Ti0);
    T[(b << 12) + (n2b << 6) + k] = pkrtz(Tr1, Ti1);
}

// Pass 2: F[k,m] = sum_n2 T[k,n2] e^{-2pi i m n2/64};
// writes Frt[b][m][k], Fit[b][m][k] (transposed, f16) = A-operand layout.
__global__ __launch_bounds__(256)
void dft_pass2(const f16x2* __restrict__ T,
               _Float16* __restrict__ Frt, _Float16* __restrict__ Fit)
{
    __shared__ f16x2  TL[4096];     // [n2][k]
    __shared__ float2 tw[64];
    const int tid = threadIdx.x;
    const int b = blockIdx.x >> 3;
    const int g = blockIdx.x & 7;

    const float4* src = (const float4*)(T + (b << 12));
    float4* dst = (float4*)TL;
#pragma unroll
    for (int i = 0; i < 4; ++i) dst[tid + (i << 8)] = src[tid + (i << 8)];
    if (tid < 64) {
        const float a = (float)tid * (1.0f / 64.0f);
        tw[tid] = make_float2(cos1_hw(a), sin1_hw(a));
    }
    __syncthreads();

    const int k  = tid & 63;           // lane = k  (coalesced output)
    const int wv = tid >> 6;
    const int ma = (g << 3) + wv;
    const int mb = ma + 4;

    float Fr0 = 0.f, Fi0 = 0.f, Fr1 = 0.f, Fi1 = 0.f;
#pragma unroll 4
    for (int n2 = 0; n2 < 64; ++n2) {
        const f16x2 t = TL[(n2 << 6) + k];      // stride-1, 2-way (free)
        const float tr = (float)t[0];
        const float ti = (float)t[1];
        const float2 wa = tw[(ma * n2) & 63];   // wave-uniform
        const float2 wb = tw[(mb * n2) & 63];
        // (tr + i ti)(c - i s) = (tr c + ti s) + i(ti c - tr s)
        Fr0 = fmaf(tr, wa.x, Fr0); Fr0 = fmaf(ti,  wa.y, Fr0);
        Fi0 = fmaf(ti, wa.x, Fi0); Fi0 = fmaf(tr, -wa.y, Fi0);
        Fr1 = fmaf(tr, wb.x, Fr1); Fr1 = fmaf(ti,  wb.y, Fr1);
        Fi1 = fmaf(ti, wb.x, Fi1); Fi1 = fmaf(tr, -wb.y, Fi1);
    }
    const int oa = (b << 12) + (ma << 6) + k;
    const int ob = (b << 12) + (mb << 6) + k;
    Frt[oa] = (_Float16)Fr0;  Fit[oa] = (_Float16)Fi0;
    Frt[ob] = (_Float16)Fr1;  Fit[ob] = (_Float16)Fi1;
}

// Main: per point p, G[p,m] = sum_k F[k,m] E1[p,k]  (4 real MFMAs per
// complex product), then red = Re sum_m G[p,m] E2[p,m] on VALU.
// MFMA layout (proven): A[row=lrow][k=quad*8+j]; B[k][col=lrow];
// D: col=lrow(p), row=quad*4+reg (m within nt).
__global__ __launch_bounds__(256, 4)
void fourier_interp_cplx(const _Float16* __restrict__ Frt,
                         const _Float16* __restrict__ Fit,
                         const float* __restrict__ xnew,
                         float* __restrict__ out)
{
    __shared__ float2 XY[512];
    const int tid    = threadIdx.x;
    const int batch  = blockIdx.x >> 5;
    const int seg    = blockIdx.x & 31;
    const int gpbase = (batch << 14) + (seg << 9);

    XY[tid]       = ((const float2*)xnew)[gpbase + tid];
    XY[tid + 256] = ((const float2*)xnew)[gpbase + tid + 256];
    __syncthreads();

    const int lane = tid & 63;
    const int wv   = tid >> 6;
    const int quad = lane >> 4;
    const int lrow = lane & 15;

    // ---- hoist F^T fragments once per wave, straight from global (L2) ----
    const _Float16* Fr = Frt + (batch << 12);
    const _Float16* Fi = Fit + (batch << 12);
    f16x8 Ar[4][2], Ai[4][2];
#pragma unroll
    for (int nt = 0; nt < 4; ++nt)
#pragma unroll
        for (int kt = 0; kt < 2; ++kt) {
            const int off = (((nt << 4) + lrow) << 6) + (kt << 5) + (quad << 3);
            Ar[nt][kt] = *(const f16x8*)(Fr + off);
            Ai[nt][kt] = *(const f16x8*)(Fi + off);
        }

#pragma unroll 1
    for (int mt = 0; mt < 8; ++mt) {
        const int mtbase = (wv << 7) + (mt << 4);
        const float2 xv = XY[mtbase + lrow];

        // rotation steps e^{2pi i x1} and e^{2pi i 2 x1}
        const float cs1 = cos1_hw(xv.x);
        const float sn1 = sin1_hw(xv.x);
        const float cs1b = fmaf(cs1, cs1, -(sn1 * sn1));
        const float sn1b = 2.0f * cs1 * sn1;

        f32x4 Gr[4], Gi[4];
#pragma unroll
        for (int nt = 0; nt < 4; ++nt) {
            Gr[nt] = (f32x4){0.f, 0.f, 0.f, 0.f};
            Gi[nt] = (f32x4){0.f, 0.f, 0.f, 0.f};
        }

#pragma unroll
        for (int kt = 0; kt < 2; ++kt) {
            // base frequency of this lane's 8-k run (never crosses k=32)
            const float fb = (float)((quad << 3) - (kt ? 32 : 0));
            float th = xv.x * fb;
            th -= floorf(th);                      // revolutions in [0,1)
            // two-seed split: even chain (j=0,2,4,6) steps by rot^2,
            // odd chain (j=1,3,5,7) likewise -> dep depth 3, 2-way ILP.
            float er0 = cos1_hw(th);
            float ei0 = sin1_hw(th);
            float er1 = fmaf(-ei0, sn1, er0 * cs1);
            float ei1 = fmaf( er0, sn1, ei0 * cs1);

            F16x8u ur, ui, un;                     // E1r, E1i, -E1i
#pragma unroll
            for (int jp = 0; jp < 4; ++jp) {
                ur.h[jp] = pkrtz(er0, er1);
                ui.h[jp] = pkrtz(ei0, ei1);
                un.h[jp] = pkrtz(-ei0, -ei1);
                if (jp < 3) {
                    const float e0 = fmaf(-ei0, sn1b, er0 * cs1b);
                    ei0 = fmaf(er0, sn1b, ei0 * cs1b);
                    er0 = e0;
                    const float e1 = fmaf(-ei1, sn1b, er1 * cs1b);
                    ei1 = fmaf(er1, sn1b, ei1 * cs1b);
                    er1 = e1;
                }
            }
#pragma unroll
            for (int nt = 0; nt < 4; ++nt) {
                Gr[nt] = __builtin_amdgcn_mfma_f32_16x16x32_f16(Ar[nt][kt], ur.v, Gr[nt], 0, 0, 0);
                Gr[nt] = __builtin_amdgcn_mfma_f32_16x16x32_f16(Ai[nt][kt], un.v, Gr[nt], 0, 0, 0);
                Gi[nt] = __builtin_amdgcn_mfma_f32_16x16x32_f16(Ar[nt][kt], ui.v, Gi[nt], 0, 0, 0);
                Gi[nt] = __builtin_amdgcn_mfma_f32_16x16x32_f16(Ai[nt][kt], ur.v, Gi[nt], 0, 0, 0);
            }
        }

        // ---- stage B: red = Re sum_m G[p,m] e^{2pi i x2 f(m)} ----
        // nt base phases by rotation from one seed:
        //   b0 = e^{2pi i x2 (quad*4)}; b1 = b0*rot16; b2 = b0*conj(rot16^2);
        //   b3 = b2*rot16.   (f(m) jumps by -64 at m=32 -> the conj(rot32).)
        const float cs2 = cos1_hw(xv.y);
        const float sn2 = sin1_hw(xv.y);
        float t16 = xv.y * 16.0f;
        t16 -= floorf(t16);
        const float c16 = cos1_hw(t16);
        const float s16 = sin1_hw(t16);
        const float cm32 = fmaf(c16, c16, -(s16 * s16));   // conj(rot16^2)
        const float sm32 = -2.0f * c16 * s16;

        float thA = xv.y * (float)(quad << 2);
        thA -= floorf(thA);
        const float erA = cos1_hw(thA);
        const float eiA = sin1_hw(thA);

        float br[4], bi[4];
        br[0] = erA;                            bi[0] = eiA;
        br[1] = fmaf(-eiA, s16, erA * c16);     bi[1] = fmaf(erA, s16, eiA * c16);
        br[2] = fmaf(-eiA, sm32, erA * cm32);   bi[2] = fmaf(erA, sm32, eiA * cm32);
        br[3] = fmaf(-bi[2], s16, br[2] * c16); bi[3] = fmaf(br[2], s16, bi[2] * c16);

        float red = 0.0f;
#pragma unroll
        for (int nt = 0; nt < 4; ++nt) {
            float er = br[nt];
            float ei = bi[nt];
#pragma unroll
            for (int reg = 0; reg < 4; ++reg) {
                red = fmaf(Gr[nt][reg],  er, red);
                red = fmaf(Gi[nt][reg], -ei, red);
                if (reg < 3) {
                    const float t2 = fmaf(-ei, sn2, er * cs2);
                    ei = fmaf(er, sn2, ei * cs2);
                    er = t2;
                }
            }
        }
        red += __shfl_xor(red, 16, 64);
        red += __shfl_xor(red, 32, 64);
        if (lane < 16)
            out[gpbase + mtbase + lane] = red * (1.0f / 4096.0f);
    }
}

extern "C" void kernel_launch(void* const* d_in, const int* in_sizes, int n_in,
                              void* d_out, int out_size, void* d_ws, size_t ws_size,
                              hipStream_t stream)
{
    const float* y    = (const float*)d_in[0];   // [32, 64, 64]
    const float* xnew = (const float*)d_in[1];   // [32, 128, 128, 2]
    float* out        = (float*)d_out;           // [32, 128, 128]

    // workspace layout (1 MiB total):
    //   T   : 32*64*64 half2  = 512 KiB
    //   Frt : 32*64*64 f16    = 256 KiB
    //   Fit : 32*64*64 f16    = 256 KiB
    f16x2*    T   = (f16x2*)d_ws;
    _Float16* Frt = (_Float16*)((char*)d_ws + (32 << 14));
    _Float16* Fit = Frt + (32 << 12);

    dft_pass1<<<256, 256, 0, stream>>>(y, T);
    dft_pass2<<<256, 256, 0, stream>>>(T, Frt, Fit);
    fourier_interp_cplx<<<1024, 256, 0, stream>>>(Frt, Fit, xnew, out);
}

// Round 4
// 87.139 us; speedup vs baseline: 1.0020x; 1.0020x over previous
//
#include <hip/hip_runtime.h>
#include <math.h>

typedef _Float16 f16x8 __attribute__((ext_vector_type(8)));
typedef _Float16 f16x2 __attribute__((ext_vector_type(2)));
typedef float    f32x4 __attribute__((ext_vector_type(4)));

union F16x8u { f16x8 v; f16x2 h[4]; };

// v_sin_f32 / v_cos_f32 take REVOLUTIONS: sin(2*pi*x) = v_sin(x).
__device__ __forceinline__ float cos1_hw(float x) { return __builtin_amdgcn_cosf(x); }
__device__ __forceinline__ float sin1_hw(float x) { return __builtin_amdgcn_sinf(x); }

// v_cvt_pkrtz_f16_f32 returns a __fp16 vector; bit-cast to our _Float16 pair.
__device__ __forceinline__ f16x2 pkrtz(float a, float b)
{
    return __builtin_bit_cast(f16x2, __builtin_amdgcn_cvt_pkrtz(a, b));
}

// ---------------------------------------------------------------------------
// Complex NUFFT via MFMA (round 10 = diagnostic restructure):
//   ynew = (1/4096) Re sum_{k,m} F[k,m] e^{2pi i x1 f(k)} e^{2pi i x2 f(m)}
// Rounds 8-9 lesson: main kernel sits at ~40 us regardless of inner-loop
// instruction mix (cot/rcp form == complex/rotation form), 4-8x above the
// throughput floor, and has NEVER appeared in the rocprof top-5 (it runs
// just under the ~40.3 us fill cutoff). This round makes one kernel
// instance = the whole job so its counters MUST surface:
//   grid 256 (1 block/CU, no tail), block 1024 (16 waves = 4 waves/SIMD,
//   same TLP as before), 4 segments per block, xnew staged once (16 KB LDS,
//   single barrier), A-fragments hoisted once per wave for all 4 segments.
// Inner math is identical to round 9.
// ---------------------------------------------------------------------------

// Pass 1: T[b][n2][k] = sum_n1 y[b,n1,n2] e^{-2pi i k n1/64}   (half2 r,i)
__global__ __launch_bounds__(256)
void dft_pass1(const float* __restrict__ y, f16x2* __restrict__ T)
{
    __shared__ float  YL[4096];
    __shared__ float2 tw[64];
    const int tid = threadIdx.x;
    const int b = blockIdx.x >> 3;
    const int g = blockIdx.x & 7;

    const float4* src = (const float4*)(y + (b << 12));
    float4* dst = (float4*)YL;
#pragma unroll
    for (int i = 0; i < 4; ++i) dst[tid + (i << 8)] = src[tid + (i << 8)];
    if (tid < 64) {
        const float a = (float)tid * (1.0f / 64.0f);
        tw[tid] = make_float2(cos1_hw(a), sin1_hw(a));
    }
    __syncthreads();

    const int k   = tid & 63;          // lane = k  (coalesced output)
    const int wv  = tid >> 6;
    const int n2a = (g << 3) + wv;
    const int n2b = n2a + 4;

    float Tr0 = 0.f, Ti0 = 0.f, Tr1 = 0.f, Ti1 = 0.f;
#pragma unroll 4
    for (int n1 = 0; n1 < 64; ++n1) {
        const float ya = YL[(n1 << 6) + n2a];   // wave-uniform -> broadcast
        const float yb = YL[(n1 << 6) + n2b];
        const float2 w = tw[(k * n1) & 63];     // e^{-i t}: (c, -s)
        Tr0 = fmaf(ya,  w.x, Tr0);
        Ti0 = fmaf(ya, -w.y, Ti0);
        Tr1 = fmaf(yb,  w.x, Tr1);
        Ti1 = fmaf(yb, -w.y, Ti1);
    }
    T[(b << 12) + (n2a << 6) + k] = pkrtz(Tr0, Ti0);
    T[(b << 12) + (n2b << 6) + k] = pkrtz(Tr1, Ti1);
}

// Pass 2: F[k,m] = sum_n2 T[k,n2] e^{-2pi i m n2/64};
// writes Frt[b][m][k], Fit[b][m][k] (transposed, f16) = A-operand layout.
__global__ __launch_bounds__(256)
void dft_pass2(const f16x2* __restrict__ T,
               _Float16* __restrict__ Frt, _Float16* __restrict__ Fit)
{
    __shared__ f16x2  TL[4096];     // [n2][k]
    __shared__ float2 tw[64];
    const int tid = threadIdx.x;
    const int b = blockIdx.x >> 3;
    const int g = blockIdx.x & 7;

    const float4* src = (const float4*)(T + (b << 12));
    float4* dst = (float4*)TL;
#pragma unroll
    for (int i = 0; i < 4; ++i) dst[tid + (i << 8)] = src[tid + (i << 8)];
    if (tid < 64) {
        const float a = (float)tid * (1.0f / 64.0f);
        tw[tid] = make_float2(cos1_hw(a), sin1_hw(a));
    }
    __syncthreads();

    const int k  = tid & 63;           // lane = k  (coalesced output)
    const int wv = tid >> 6;
    const int ma = (g << 3) + wv;
    const int mb = ma + 4;

    float Fr0 = 0.f, Fi0 = 0.f, Fr1 = 0.f, Fi1 = 0.f;
#pragma unroll 4
    for (int n2 = 0; n2 < 64; ++n2) {
        const f16x2 t = TL[(n2 << 6) + k];      // stride-1, 2-way (free)
        const float tr = (float)t[0];
        const float ti = (float)t[1];
        const float2 wa = tw[(ma * n2) & 63];   // wave-uniform
        const float2 wb = tw[(mb * n2) & 63];
        // (tr + i ti)(c - i s) = (tr c + ti s) + i(ti c - tr s)
        Fr0 = fmaf(tr, wa.x, Fr0); Fr0 = fmaf(ti,  wa.y, Fr0);
        Fi0 = fmaf(ti, wa.x, Fi0); Fi0 = fmaf(tr, -wa.y, Fi0);
        Fr1 = fmaf(tr, wb.x, Fr1); Fr1 = fmaf(ti,  wb.y, Fr1);
        Fi1 = fmaf(ti, wb.x, Fi1); Fi1 = fmaf(tr, -wb.y, Fi1);
    }
    const int oa = (b << 12) + (ma << 6) + k;
    const int ob = (b << 12) + (mb << 6) + k;
    Frt[oa] = (_Float16)Fr0;  Fit[oa] = (_Float16)Fi0;
    Frt[ob] = (_Float16)Fr1;  Fit[ob] = (_Float16)Fi1;
}

// Main: per point p, G[p,m] = sum_k F[k,m] E1[p,k]  (4 real MFMAs per
// complex product), then red = Re sum_m G[p,m] E2[p,m] on VALU.
// MFMA layout (proven): A[row=lrow][k=quad*8+j]; B[k][col=lrow];
// D: col=lrow(p), row=quad*4+reg (m within nt).
// Grid 256 x block 1024: one block per CU, 4 segments (2048 points) each;
// mt = sg*2 + tile: wave wv owns points sg*512 + wv*32 + tile*16 + lrow.
__global__ __launch_bounds__(1024, 4)
void fourier_interp_cplx(const _Float16* __restrict__ Frt,
                         const _Float16* __restrict__ Fit,
                         const float* __restrict__ xnew,
                         float* __restrict__ out)
{
    __shared__ float2 XY[2048];
    const int tid    = threadIdx.x;
    const int batch  = blockIdx.x >> 3;
    const int sgrp   = blockIdx.x & 7;       // 8 blocks per batch
    const int pbase  = (batch << 14) + (sgrp << 11);   // 2048 points

    XY[tid]        = ((const float2*)xnew)[pbase + tid];
    XY[tid + 1024] = ((const float2*)xnew)[pbase + tid + 1024];
    __syncthreads();

    const int lane = tid & 63;
    const int wv   = tid >> 6;               // 0..15
    const int quad = lane >> 4;
    const int lrow = lane & 15;

    // ---- hoist F^T fragments once per wave (covers all 4 segments) ----
    const _Float16* Fr = Frt + (batch << 12);
    const _Float16* Fi = Fit + (batch << 12);
    f16x8 Ar[4][2], Ai[4][2];
#pragma unroll
    for (int nt = 0; nt < 4; ++nt)
#pragma unroll
        for (int kt = 0; kt < 2; ++kt) {
            const int off = (((nt << 4) + lrow) << 6) + (kt << 5) + (quad << 3);
            Ar[nt][kt] = *(const f16x8*)(Fr + off);
            Ai[nt][kt] = *(const f16x8*)(Fi + off);
        }

#pragma unroll 1
    for (int mt = 0; mt < 8; ++mt) {
        // local point index of this lane's tile
        const int lpt = ((mt >> 1) << 9) + (wv << 5) + ((mt & 1) << 4);
        const float2 xv = XY[lpt + lrow];

        // rotation steps e^{2pi i x1} and e^{2pi i 2 x1}
        const float cs1 = cos1_hw(xv.x);
        const float sn1 = sin1_hw(xv.x);
        const float cs1b = fmaf(cs1, cs1, -(sn1 * sn1));
        const float sn1b = 2.0f * cs1 * sn1;

        f32x4 Gr[4], Gi[4];
#pragma unroll
        for (int nt = 0; nt < 4; ++nt) {
            Gr[nt] = (f32x4){0.f, 0.f, 0.f, 0.f};
            Gi[nt] = (f32x4){0.f, 0.f, 0.f, 0.f};
        }

#pragma unroll
        for (int kt = 0; kt < 2; ++kt) {
            // base frequency of this lane's 8-k run (never crosses k=32)
            const float fb = (float)((quad << 3) - (kt ? 32 : 0));
            float th = xv.x * fb;
            th -= floorf(th);                      // revolutions in [0,1)
            // two-seed split: even chain steps by rot^2, odd chain likewise
            float er0 = cos1_hw(th);
            float ei0 = sin1_hw(th);
            float er1 = fmaf(-ei0, sn1, er0 * cs1);
            float ei1 = fmaf( er0, sn1, ei0 * cs1);

            F16x8u ur, ui, un;                     // E1r, E1i, -E1i
#pragma unroll
            for (int jp = 0; jp < 4; ++jp) {
                ur.h[jp] = pkrtz(er0, er1);
                ui.h[jp] = pkrtz(ei0, ei1);
                un.h[jp] = pkrtz(-ei0, -ei1);
                if (jp < 3) {
                    const float e0 = fmaf(-ei0, sn1b, er0 * cs1b);
                    ei0 = fmaf(er0, sn1b, ei0 * cs1b);
                    er0 = e0;
                    const float e1 = fmaf(-ei1, sn1b, er1 * cs1b);
                    ei1 = fmaf(er1, sn1b, ei1 * cs1b);
                    er1 = e1;
                }
            }
#pragma unroll
            for (int nt = 0; nt < 4; ++nt) {
                Gr[nt] = __builtin_amdgcn_mfma_f32_16x16x32_f16(Ar[nt][kt], ur.v, Gr[nt], 0, 0, 0);
                Gr[nt] = __builtin_amdgcn_mfma_f32_16x16x32_f16(Ai[nt][kt], un.v, Gr[nt], 0, 0, 0);
                Gi[nt] = __builtin_amdgcn_mfma_f32_16x16x32_f16(Ar[nt][kt], ui.v, Gi[nt], 0, 0, 0);
                Gi[nt] = __builtin_amdgcn_mfma_f32_16x16x32_f16(Ai[nt][kt], ur.v, Gi[nt], 0, 0, 0);
            }
        }

        // ---- stage B: red = Re sum_m G[p,m] e^{2pi i x2 f(m)} ----
        const float cs2 = cos1_hw(xv.y);
        const float sn2 = sin1_hw(xv.y);
        float t16 = xv.y * 16.0f;
        t16 -= floorf(t16);
        const float c16 = cos1_hw(t16);
        const float s16 = sin1_hw(t16);
        const float cm32 = fmaf(c16, c16, -(s16 * s16));   // conj(rot16^2)
        const float sm32 = -2.0f * c16 * s16;

        float thA = xv.y * (float)(quad << 2);
        thA -= floorf(thA);
        const float erA = cos1_hw(thA);
        const float eiA = sin1_hw(thA);

        float br[4], bi[4];
        br[0] = erA;                            bi[0] = eiA;
        br[1] = fmaf(-eiA, s16, erA * c16);     bi[1] = fmaf(erA, s16, eiA * c16);
        br[2] = fmaf(-eiA, sm32, erA * cm32);   bi[2] = fmaf(erA, sm32, eiA * cm32);
        br[3] = fmaf(-bi[2], s16, br[2] * c16); bi[3] = fmaf(br[2], s16, bi[2] * c16);

        float red = 0.0f;
#pragma unroll
        for (int nt = 0; nt < 4; ++nt) {
            float er = br[nt];
            float ei = bi[nt];
#pragma unroll
            for (int reg = 0; reg < 4; ++reg) {
                red = fmaf(Gr[nt][reg],  er, red);
                red = fmaf(Gi[nt][reg], -ei, red);
                if (reg < 3) {
                    const float t2 = fmaf(-ei, sn2, er * cs2);
                    ei = fmaf(er, sn2, ei * cs2);
                    er = t2;
                }
            }
        }
        red += __shfl_xor(red, 16, 64);
        red += __shfl_xor(red, 32, 64);
        if (lane < 16)
            out[pbase + lpt + lane] = red * (1.0f / 4096.0f);
    }
}

extern "C" void kernel_launch(void* const* d_in, const int* in_sizes, int n_in,
                              void* d_out, int out_size, void* d_ws, size_t ws_size,
                              hipStream_t stream)
{
    const float* y    = (const float*)d_in[0];   // [32, 64, 64]
    const float* xnew = (const float*)d_in[1];   // [32, 128, 128, 2]
    float* out        = (float*)d_out;           // [32, 128, 128]

    // workspace layout (1 MiB used):
    //   T   : 32*64*64 half2  = 512 KiB
    //   Frt : 32*64*64 f16    = 256 KiB
    //   Fit : 32*64*64 f16    = 256 KiB
    f16x2*    T   = (f16x2*)d_ws;
    _Float16* Frt = (_Float16*)((char*)d_ws + (32 << 14));
    _Float16* Fit = Frt + (32 << 12);

    dft_pass1<<<256, 256, 0, stream>>>(y, T);
    dft_pass2<<<256, 256, 0, stream>>>(T, Frt, Fit);
    fourier_interp_cplx<<<256, 1024, 0, stream>>>(Frt, Fit, xnew, out);
}